// Round 1
// baseline (639.571 us; speedup 1.0000x reference)
//
#include <hip/hip_runtime.h>
#include <hip/hip_bf16.h>

#define FDIM 128

// ---------------- degree count ----------------
__global__ __launch_bounds__(256) void deg_kernel(const int* __restrict__ dst, int* __restrict__ cnt, int E) {
    int e = blockIdx.x * 256 + threadIdx.x;
    if (e < E) atomicAdd(&cnt[dst[e]], 1);
}

// ---------------- scan phase A: per-block sums (chunk = 1024) ----------------
__global__ __launch_bounds__(256) void scan_partial(const int* __restrict__ cnt, int* __restrict__ bsum, int n) {
    __shared__ int sdata[256];
    int b = blockIdx.x, t = threadIdx.x;
    int base = b * 1024;
    int s = 0;
    for (int i = 0; i < 4; i++) {
        int idx = base + t * 4 + i;
        if (idx < n) s += cnt[idx];
    }
    sdata[t] = s;
    __syncthreads();
    for (int off = 128; off > 0; off >>= 1) {
        if (t < off) sdata[t] += sdata[t + off];
        __syncthreads();
    }
    if (t == 0) bsum[b] = sdata[0];
}

// ---------------- scan phase B: serial scan of block sums (nb ~ 79) ----------------
__global__ void scan_sums(int* __restrict__ bsum, int nb) {
    if (threadIdx.x == 0 && blockIdx.x == 0) {
        int acc = 0;
        for (int i = 0; i < nb; i++) { int v = bsum[i]; bsum[i] = acc; acc += v; }
    }
}

// ---------------- scan phase C: exclusive scan within chunk + offset ----------------
__global__ __launch_bounds__(256) void scan_final(const int* __restrict__ cnt, const int* __restrict__ bsum,
                                                  int* __restrict__ rowptr, int n, int E) {
    __shared__ int sdata[256];
    int b = blockIdx.x, t = threadIdx.x;
    int base = b * 1024;
    int loc[4];
    int s = 0;
    for (int i = 0; i < 4; i++) {
        int idx = base + t * 4 + i;
        int v = (idx < n) ? cnt[idx] : 0;
        loc[i] = s;
        s += v;
    }
    sdata[t] = s;
    __syncthreads();
    // Hillis-Steele inclusive scan over 256 thread totals
    for (int off = 1; off < 256; off <<= 1) {
        int v = (t >= off) ? sdata[t - off] : 0;
        __syncthreads();
        sdata[t] += v;
        __syncthreads();
    }
    int texc = sdata[t] - s;  // exclusive prefix of this thread within block
    int boff = bsum[b];
    for (int i = 0; i < 4; i++) {
        int idx = base + t * 4 + i;
        if (idx < n) rowptr[idx] = boff + texc + loc[i];
    }
    if (b == 0 && t == 0) rowptr[n] = E;
}

// ---------------- dinv = rsqrt(deg), deg = cnt + 1 (self-loop) ----------------
__global__ __launch_bounds__(256) void deg_dinv(const int* __restrict__ cnt, float* __restrict__ dinv, int n) {
    int i = blockIdx.x * 256 + threadIdx.x;
    if (i < n) dinv[i] = rsqrtf((float)(cnt[i] + 1));
}

// ---------------- CSR fill (order within bucket irrelevant) ----------------
__global__ __launch_bounds__(256) void fill_kernel(const int* __restrict__ srcI, const int* __restrict__ dstI,
                                                   const int* __restrict__ rowptr, int* __restrict__ fill,
                                                   int* __restrict__ col, int E) {
    int e = blockIdx.x * 256 + threadIdx.x;
    if (e < E) {
        int d = dstI[e];
        int pos = rowptr[d] + atomicAdd(&fill[d], 1);
        col[pos] = srcI[e];
    }
}

// ---------------- GEMM: Y[r] = (X @ W)[r] * dinv[r]  (X: n x 128, W: 128 x 128) ----------------
// block 256 threads, tile 32 rows x 128 cols, each thread 4x4 outputs.
__global__ __launch_bounds__(256, 3) void gemm_scale(const float* __restrict__ X, const float* __restrict__ W,
                                                     const float* __restrict__ dinv, float* __restrict__ Y, int n) {
    __shared__ float Wl[64][128];   // 32 KB (half of K staged at a time)
    __shared__ float Xs[32][129];   // 16.5 KB, padded
    int t = threadIdx.x;
    int tx = t & 31, ty = t >> 5;
    int row0 = blockIdx.x * 32;

    // stage X tile (clamped for safety; N % 32 == 0 in practice)
    float4 xst[4];
    for (int i = 0; i < 4; i++) {
        int v = t + i * 256;          // float4 slot 0..1023
        int r = v >> 5;
        int rg = row0 + r;
        if (rg >= n) rg = n - 1;
        const float4* rowp = (const float4*)(X + (size_t)rg * FDIM);
        xst[i] = rowp[v & 31];
    }
    for (int i = 0; i < 4; i++) {
        int v = t + i * 256;
        int r = v >> 5, c = (v & 31) << 2;
        Xs[r][c + 0] = xst[i].x; Xs[r][c + 1] = xst[i].y;
        Xs[r][c + 2] = xst[i].z; Xs[r][c + 3] = xst[i].w;
    }

    float acc[4][4] = {};
    for (int kb = 0; kb < 2; kb++) {
        __syncthreads();   // Xs ready (kb=0) / previous Wl reads done (kb=1)
        const float4* W4 = (const float4*)(W + (size_t)kb * 64 * FDIM);
        for (int i = 0; i < 8; i++) {
            int v = t + i * 256;
            int r = v >> 5, c = (v & 31) << 2;
            *(float4*)&Wl[r][c] = W4[v];
        }
        __syncthreads();
        #pragma unroll 8
        for (int k = 0; k < 64; k++) {
            float4 w = *(const float4*)&Wl[k][tx << 2];
            float x0 = Xs[(ty << 2) + 0][(kb << 6) + k];
            float x1 = Xs[(ty << 2) + 1][(kb << 6) + k];
            float x2 = Xs[(ty << 2) + 2][(kb << 6) + k];
            float x3 = Xs[(ty << 2) + 3][(kb << 6) + k];
            acc[0][0] += x0 * w.x; acc[0][1] += x0 * w.y; acc[0][2] += x0 * w.z; acc[0][3] += x0 * w.w;
            acc[1][0] += x1 * w.x; acc[1][1] += x1 * w.y; acc[1][2] += x1 * w.z; acc[1][3] += x1 * w.w;
            acc[2][0] += x2 * w.x; acc[2][1] += x2 * w.y; acc[2][2] += x2 * w.z; acc[2][3] += x2 * w.w;
            acc[3][0] += x3 * w.x; acc[3][1] += x3 * w.y; acc[3][2] += x3 * w.z; acc[3][3] += x3 * w.w;
        }
    }

    for (int i = 0; i < 4; i++) {
        int r = row0 + (ty << 2) + i;
        if (r < n) {
            float s = dinv[r];
            float4 o;
            o.x = acc[i][0] * s; o.y = acc[i][1] * s; o.z = acc[i][2] * s; o.w = acc[i][3] * s;
            *(float4*)&Y[(size_t)r * FDIM + (tx << 2)] = o;
        }
    }
}

// ---------------- aggregation: out[j] = act(dinv[j]*(T0[j] + sum_{s->j} T0[s]) + bias) ----------------
// MODE 0: relu -> h; MODE 1: identity -> mu; MODE 2: identity -> logvar, plus z = eps*exp(0.5*lv)+mu;
// MODE 3: sigmoid -> recon.
// 8 nodes per block, 32 lanes per node, float4 (4 features) per lane.
template <int MODE>
__global__ __launch_bounds__(256) void agg_kernel(const float* __restrict__ T0, const int* __restrict__ rowptr,
                                                  const int* __restrict__ col, const float* __restrict__ dinv,
                                                  const float* __restrict__ bias, float* __restrict__ out,
                                                  const float* __restrict__ eps, const float* __restrict__ mu,
                                                  float* __restrict__ z, int n) {
    int t = threadIdx.x;
    int lane = t & 31;
    int node = blockIdx.x * 8 + (t >> 5);
    if (node >= n) return;

    const float4* T4 = (const float4*)T0;
    size_t oidx = (size_t)node * 32 + lane;
    float4 acc = T4[oidx];  // self-loop term (already dinv-scaled)
    int rp0 = rowptr[node], rp1 = rowptr[node + 1];

    for (int eb = rp0; eb < rp1; eb += 32) {
        int e = eb + lane;
        int myc = (e < rp1) ? col[e] : 0;
        int m = rp1 - eb; if (m > 32) m = 32;
        for (int i = 0; i < m; i++) {
            int s = __shfl(myc, i, 32);
            float4 v = T4[(size_t)s * 32 + lane];
            acc.x += v.x; acc.y += v.y; acc.z += v.z; acc.w += v.w;
        }
    }

    float dj = dinv[node];
    float4 bb = ((const float4*)bias)[lane];
    float4 r;
    r.x = acc.x * dj + bb.x;
    r.y = acc.y * dj + bb.y;
    r.z = acc.z * dj + bb.z;
    r.w = acc.w * dj + bb.w;

    if (MODE == 0) {
        r.x = fmaxf(r.x, 0.f); r.y = fmaxf(r.y, 0.f); r.z = fmaxf(r.z, 0.f); r.w = fmaxf(r.w, 0.f);
        ((float4*)out)[oidx] = r;
    } else if (MODE == 1) {
        ((float4*)out)[oidx] = r;
    } else if (MODE == 2) {
        ((float4*)out)[oidx] = r;  // logvar
        float4 e4 = ((const float4*)eps)[oidx];
        float4 m4 = ((const float4*)mu)[oidx];
        float4 zz;
        zz.x = e4.x * expf(0.5f * r.x) + m4.x;
        zz.y = e4.y * expf(0.5f * r.y) + m4.y;
        zz.z = e4.z * expf(0.5f * r.z) + m4.z;
        zz.w = e4.w * expf(0.5f * r.w) + m4.w;
        ((float4*)z)[oidx] = zz;
    } else {
        r.x = 1.f / (1.f + expf(-r.x));
        r.y = 1.f / (1.f + expf(-r.y));
        r.z = 1.f / (1.f + expf(-r.z));
        r.w = 1.f / (1.f + expf(-r.w));
        ((float4*)out)[oidx] = r;
    }
}

extern "C" void kernel_launch(void* const* d_in, const int* in_sizes, int n_in,
                              void* d_out, int out_size, void* d_ws, size_t ws_size,
                              hipStream_t stream) {
    const int F = FDIM;
    const int N = in_sizes[0] / F;
    const int E = in_sizes[1] / 2;

    const float* x   = (const float*)d_in[0];
    const int*   ei  = (const int*)d_in[1];
    const int*   srcI = ei;
    const int*   dstI = ei + E;
    const float* eps = (const float*)d_in[2];
    const float* W1  = (const float*)d_in[3];
    const float* b1  = (const float*)d_in[4];
    const float* Wmu = (const float*)d_in[5];
    const float* bmu = (const float*)d_in[6];
    const float* Wlv = (const float*)d_in[7];
    const float* blv = (const float*)d_in[8];

    float* recon = (float*)d_out;
    size_t NF = (size_t)N * F;
    float* muO = recon + NF;
    float* lvO = recon + 2 * NF;

    // workspace carve-out (256B aligned)
    size_t off = 0;
    auto alloc = [&](size_t bytes) -> void* {
        void* p = (char*)d_ws + off;
        off += (bytes + 255) & ~(size_t)255;
        return p;
    };
    int*   cnt    = (int*)alloc((size_t)N * 4);
    int*   rowptr = (int*)alloc((size_t)(N + 1) * 4);
    int*   fillc  = (int*)alloc((size_t)N * 4);
    int*   bsum   = (int*)alloc(4096);
    int*   col    = (int*)alloc((size_t)E * 4);
    float* dinv   = (float*)alloc((size_t)N * 4);
    float* t0     = (float*)alloc(NF * 4);
    float* z      = (float*)alloc(NF * 4);
    float* h      = recon;  // use recon slot as scratch for h until the last kernel

    hipMemsetAsync(cnt, 0, (size_t)N * 4, stream);
    hipMemsetAsync(fillc, 0, (size_t)N * 4, stream);

    int eb = (E + 255) / 256;
    int NB = (N + 1023) / 1024;
    deg_kernel<<<eb, 256, 0, stream>>>(dstI, cnt, E);
    scan_partial<<<NB, 256, 0, stream>>>(cnt, bsum, N);
    scan_sums<<<1, 64, 0, stream>>>(bsum, NB);
    scan_final<<<NB, 256, 0, stream>>>(cnt, bsum, rowptr, N, E);
    deg_dinv<<<(N + 255) / 256, 256, 0, stream>>>(cnt, dinv, N);
    fill_kernel<<<eb, 256, 0, stream>>>(srcI, dstI, rowptr, fillc, col, E);

    int gb = (N + 31) / 32;
    int ab = (N + 7) / 8;

    // conv1: h = relu(agg(x @ W1)) -> h (in recon slot)
    gemm_scale<<<gb, 256, 0, stream>>>(x, W1, dinv, t0, N);
    agg_kernel<0><<<ab, 256, 0, stream>>>(t0, rowptr, col, dinv, b1, h, nullptr, nullptr, nullptr, N);
    // conv2: mu
    gemm_scale<<<gb, 256, 0, stream>>>(h, Wmu, dinv, t0, N);
    agg_kernel<1><<<ab, 256, 0, stream>>>(t0, rowptr, col, dinv, bmu, muO, nullptr, nullptr, nullptr, N);
    // conv3: logvar (+ z = eps*exp(0.5*lv) + mu)
    gemm_scale<<<gb, 256, 0, stream>>>(h, Wlv, dinv, t0, N);
    agg_kernel<2><<<ab, 256, 0, stream>>>(t0, rowptr, col, dinv, blv, lvO, eps, muO, z, N);
    // conv4: recon = sigmoid(agg(z @ W1)) (overwrites h scratch)
    gemm_scale<<<gb, 256, 0, stream>>>(z, W1, dinv, t0, N);
    agg_kernel<3><<<ab, 256, 0, stream>>>(t0, rowptr, col, dinv, b1, recon, nullptr, nullptr, nullptr, N);
}

// Round 2
// 467.962 us; speedup vs baseline: 1.3667x; 1.3667x over previous
//
#include <hip/hip_runtime.h>
#include <hip/hip_bf16.h>

#define FDIM 128

typedef __attribute__((ext_vector_type(8))) short short8;
typedef __attribute__((ext_vector_type(4))) float f32x4;

__device__ inline float bflo(unsigned u) { return __uint_as_float(u << 16); }
__device__ inline float bfhi(unsigned u) { return __uint_as_float(u & 0xffff0000u); }
__device__ inline unsigned short f2bf(float f) {
    unsigned u = __float_as_uint(f);
    u += 0x7fffu + ((u >> 16) & 1u);   // RNE
    return (unsigned short)(u >> 16);
}
__device__ inline unsigned pack2(float a, float b) {
    return (unsigned)f2bf(a) | ((unsigned)f2bf(b) << 16);
}

// ---------------- degree count ----------------
__global__ __launch_bounds__(256) void deg_kernel(const int* __restrict__ dst, int* __restrict__ cnt, int E) {
    int e = blockIdx.x * 256 + threadIdx.x;
    if (e < E) atomicAdd(&cnt[dst[e]], 1);
}

// ---------------- scan phase A: per-block sums (chunk = 1024) ----------------
__global__ __launch_bounds__(256) void scan_partial(const int* __restrict__ cnt, int* __restrict__ bsum, int n) {
    __shared__ int sdata[256];
    int b = blockIdx.x, t = threadIdx.x;
    int base = b * 1024;
    int s = 0;
    for (int i = 0; i < 4; i++) {
        int idx = base + t * 4 + i;
        if (idx < n) s += cnt[idx];
    }
    sdata[t] = s;
    __syncthreads();
    for (int off = 128; off > 0; off >>= 1) {
        if (t < off) sdata[t] += sdata[t + off];
        __syncthreads();
    }
    if (t == 0) bsum[b] = sdata[0];
}

// ---------------- scan phase B: parallel exclusive scan of block sums (nb <= 256) ----------------
__global__ __launch_bounds__(256) void scan_sums(int* __restrict__ bsum, int nb) {
    __shared__ int sdata[256];
    int t = threadIdx.x;
    int v = (t < nb) ? bsum[t] : 0;
    sdata[t] = v;
    __syncthreads();
    for (int off = 1; off < 256; off <<= 1) {
        int u = (t >= off) ? sdata[t - off] : 0;
        __syncthreads();
        sdata[t] += u;
        __syncthreads();
    }
    if (t < nb) bsum[t] = sdata[t] - v;   // exclusive
}

// ---------------- scan phase C: exclusive scan within chunk + offset ----------------
__global__ __launch_bounds__(256) void scan_final(const int* __restrict__ cnt, const int* __restrict__ bsum,
                                                  int* __restrict__ rowptr, int n, int E) {
    __shared__ int sdata[256];
    int b = blockIdx.x, t = threadIdx.x;
    int base = b * 1024;
    int loc[4];
    int s = 0;
    for (int i = 0; i < 4; i++) {
        int idx = base + t * 4 + i;
        int v = (idx < n) ? cnt[idx] : 0;
        loc[i] = s;
        s += v;
    }
    sdata[t] = s;
    __syncthreads();
    for (int off = 1; off < 256; off <<= 1) {
        int v = (t >= off) ? sdata[t - off] : 0;
        __syncthreads();
        sdata[t] += v;
        __syncthreads();
    }
    int texc = sdata[t] - s;
    int boff = bsum[b];
    for (int i = 0; i < 4; i++) {
        int idx = base + t * 4 + i;
        if (idx < n) rowptr[idx] = boff + texc + loc[i];
    }
    if (b == 0 && t == 0) rowptr[n] = E;
}

// ---------------- dinv = rsqrt(deg), deg = cnt + 1 (self-loop) ----------------
__global__ __launch_bounds__(256) void deg_dinv(const int* __restrict__ cnt, float* __restrict__ dinv, int n) {
    int i = blockIdx.x * 256 + threadIdx.x;
    if (i < n) dinv[i] = rsqrtf((float)(cnt[i] + 1));
}

// ---------------- CSR fill ----------------
__global__ __launch_bounds__(256) void fill_kernel(const int* __restrict__ srcI, const int* __restrict__ dstI,
                                                   const int* __restrict__ rowptr, int* __restrict__ fill,
                                                   int* __restrict__ col, int E) {
    int e = blockIdx.x * 256 + threadIdx.x;
    if (e < E) {
        int d = dstI[e];
        int pos = rowptr[d] + atomicAdd(&fill[d], 1);
        col[pos] = srcI[e];
    }
}

// ---------------- MFMA GEMM: Y(bf16)[r] = (X @ W)[r] * dinv[r] ----------------
// X: n x 128 (fp32 if !BF16IN else bf16), W: 128 x 128 fp32 row-major [k][n].
// Block: 256 threads = 4 waves, 64 rows/block; wave handles 16 rows x 128 cols
// via 8 col-tiles of 16x16x32 bf16 MFMA, K-loop of 4.
template<bool BF16IN>
__global__ __launch_bounds__(256) void gemm_mfma(const void* __restrict__ Xv, const float* __restrict__ W,
                                                 const float* __restrict__ dinv, unsigned short* __restrict__ Y,
                                                 int n) {
    __shared__ unsigned short Wt[128][136];   // transposed W in bf16, +8 pad (2-way bank alias = free)
    int t = threadIdx.x;
    #pragma unroll 4
    for (int i = 0; i < 64; i++) {
        int idx = i * 256 + t;
        int r = idx >> 7, c = idx & 127;
        Wt[c][r] = f2bf(W[idx]);
    }
    __syncthreads();

    int wave = t >> 6, lane = t & 63;
    int quad = lane >> 4, mrow = lane & 15;
    int row0 = blockIdx.x * 64 + wave * 16;
    int gr = row0 + mrow; if (gr >= n) gr = n - 1;

    f32x4 acc[8];
    #pragma unroll
    for (int i = 0; i < 8; i++) acc[i] = (f32x4){0.f, 0.f, 0.f, 0.f};

    #pragma unroll
    for (int kb = 0; kb < 4; kb++) {
        int k0 = kb * 32 + quad * 8;
        short8 a;
        if (BF16IN) {
            union { uint4 u4; short8 s8; } cv;
            cv.u4 = *(const uint4*)((const unsigned short*)Xv + (size_t)gr * FDIM + k0);
            a = cv.s8;
        } else {
            const float* xp = (const float*)Xv + (size_t)gr * FDIM + k0;
            float4 f0 = *(const float4*)xp;
            float4 f1 = *(const float4*)(xp + 4);
            union { unsigned u[4]; short8 s8; } cv;
            cv.u[0] = pack2(f0.x, f0.y); cv.u[1] = pack2(f0.z, f0.w);
            cv.u[2] = pack2(f1.x, f1.y); cv.u[3] = pack2(f1.z, f1.w);
            a = cv.s8;
        }
        #pragma unroll
        for (int tile = 0; tile < 8; tile++) {
            short8 b = *(const short8*)&Wt[tile * 16 + mrow][k0];
            acc[tile] = __builtin_amdgcn_mfma_f32_16x16x32_bf16(a, b, acc[tile], 0, 0, 0);
        }
    }

    // C/D layout: col = lane&15, row = quad*4 + reg
    #pragma unroll
    for (int r = 0; r < 4; r++) {
        int rowg = row0 + quad * 4 + r;
        if (rowg < n) {
            float dj = dinv[rowg];
            #pragma unroll
            for (int tile = 0; tile < 8; tile++)
                Y[(size_t)rowg * FDIM + tile * 16 + mrow] = f2bf(acc[tile][r] * dj);
        }
    }
}

// ---------------- aggregation over bf16 rows ----------------
// out[j] = act(dinv[j]*(T0[j] + sum_{s->j} T0[s]) + bias)
// 16 nodes/block, 16 lanes/node, 8 features (1x uint4 = 8 bf16) per lane.
// MODE 0: relu -> bf16 outB (h).  MODE 1: fp32 outF (mu).
// MODE 2: fp32 outF (logvar) + z=eps*exp(0.5*lv)+mu -> bf16 outB.
// MODE 3: sigmoid -> fp32 outF (recon).
template<int MODE>
__global__ __launch_bounds__(256) void agg_bf16(const uint4* __restrict__ T0, const int* __restrict__ rowptr,
                                                const int* __restrict__ col, const float* __restrict__ dinv,
                                                const float* __restrict__ bias, float* __restrict__ outF,
                                                unsigned short* __restrict__ outB, const float* __restrict__ eps,
                                                const float* __restrict__ mu, int n) {
    int t = threadIdx.x;
    int lane16 = t & 15;
    int node = blockIdx.x * 16 + (t >> 4);
    if (node >= n) return;

    size_t ridx = (size_t)node * 16 + lane16;
    float acc[8];
    {
        uint4 v = T0[ridx];  // self-loop term (already dinv-scaled)
        acc[0] = bflo(v.x); acc[1] = bfhi(v.x); acc[2] = bflo(v.y); acc[3] = bfhi(v.y);
        acc[4] = bflo(v.z); acc[5] = bfhi(v.z); acc[6] = bflo(v.w); acc[7] = bfhi(v.w);
    }

    int rp0 = rowptr[node], rp1 = rowptr[node + 1];
    for (int eb = rp0; eb < rp1; eb += 16) {
        int e = eb + lane16;
        int myc = (e < rp1) ? col[e] : 0;
        int m = rp1 - eb; if (m > 16) m = 16;
        for (int i = 0; i < m; i++) {
            int s = __shfl(myc, i, 16);
            uint4 v = T0[(size_t)s * 16 + lane16];
            acc[0] += bflo(v.x); acc[1] += bfhi(v.x); acc[2] += bflo(v.y); acc[3] += bfhi(v.y);
            acc[4] += bflo(v.z); acc[5] += bfhi(v.z); acc[6] += bflo(v.w); acc[7] += bfhi(v.w);
        }
    }

    float dj = dinv[node];
    float4 b0 = *(const float4*)(bias + lane16 * 8);
    float4 b1 = *(const float4*)(bias + lane16 * 8 + 4);
    float r[8];
    r[0] = acc[0] * dj + b0.x; r[1] = acc[1] * dj + b0.y;
    r[2] = acc[2] * dj + b0.z; r[3] = acc[3] * dj + b0.w;
    r[4] = acc[4] * dj + b1.x; r[5] = acc[5] * dj + b1.y;
    r[6] = acc[6] * dj + b1.z; r[7] = acc[7] * dj + b1.w;

    size_t fo = (size_t)node * FDIM + lane16 * 8;
    if (MODE == 0) {
        uint4 o;
        o.x = pack2(fmaxf(r[0], 0.f), fmaxf(r[1], 0.f));
        o.y = pack2(fmaxf(r[2], 0.f), fmaxf(r[3], 0.f));
        o.z = pack2(fmaxf(r[4], 0.f), fmaxf(r[5], 0.f));
        o.w = pack2(fmaxf(r[6], 0.f), fmaxf(r[7], 0.f));
        ((uint4*)outB)[ridx] = o;
    } else if (MODE == 1) {
        *(float4*)(outF + fo)     = (float4){r[0], r[1], r[2], r[3]};
        *(float4*)(outF + fo + 4) = (float4){r[4], r[5], r[6], r[7]};
    } else if (MODE == 2) {
        *(float4*)(outF + fo)     = (float4){r[0], r[1], r[2], r[3]};
        *(float4*)(outF + fo + 4) = (float4){r[4], r[5], r[6], r[7]};
        float4 e0 = *(const float4*)(eps + fo), e1 = *(const float4*)(eps + fo + 4);
        float4 m0 = *(const float4*)(mu + fo),  m1 = *(const float4*)(mu + fo + 4);
        float z0 = e0.x * expf(0.5f * r[0]) + m0.x;
        float z1 = e0.y * expf(0.5f * r[1]) + m0.y;
        float z2 = e0.z * expf(0.5f * r[2]) + m0.z;
        float z3 = e0.w * expf(0.5f * r[3]) + m0.w;
        float z4 = e1.x * expf(0.5f * r[4]) + m1.x;
        float z5 = e1.y * expf(0.5f * r[5]) + m1.y;
        float z6 = e1.z * expf(0.5f * r[6]) + m1.z;
        float z7 = e1.w * expf(0.5f * r[7]) + m1.w;
        uint4 o;
        o.x = pack2(z0, z1); o.y = pack2(z2, z3); o.z = pack2(z4, z5); o.w = pack2(z6, z7);
        ((uint4*)outB)[ridx] = o;
    } else {
        *(float4*)(outF + fo) = (float4){1.f / (1.f + expf(-r[0])), 1.f / (1.f + expf(-r[1])),
                                         1.f / (1.f + expf(-r[2])), 1.f / (1.f + expf(-r[3]))};
        *(float4*)(outF + fo + 4) = (float4){1.f / (1.f + expf(-r[4])), 1.f / (1.f + expf(-r[5])),
                                             1.f / (1.f + expf(-r[6])), 1.f / (1.f + expf(-r[7]))};
    }
}

extern "C" void kernel_launch(void* const* d_in, const int* in_sizes, int n_in,
                              void* d_out, int out_size, void* d_ws, size_t ws_size,
                              hipStream_t stream) {
    const int F = FDIM;
    const int N = in_sizes[0] / F;
    const int E = in_sizes[1] / 2;

    const float* x   = (const float*)d_in[0];
    const int*   ei  = (const int*)d_in[1];
    const int*   srcI = ei;
    const int*   dstI = ei + E;
    const float* eps = (const float*)d_in[2];
    const float* W1  = (const float*)d_in[3];
    const float* b1  = (const float*)d_in[4];
    const float* Wmu = (const float*)d_in[5];
    const float* bmu = (const float*)d_in[6];
    const float* Wlv = (const float*)d_in[7];
    const float* blv = (const float*)d_in[8];

    float* recon = (float*)d_out;
    size_t NF = (size_t)N * F;
    float* muO = recon + NF;
    float* lvO = recon + 2 * NF;

    size_t off = 0;
    auto alloc = [&](size_t bytes) -> void* {
        void* p = (char*)d_ws + off;
        off += (bytes + 255) & ~(size_t)255;
        return p;
    };
    int*   cnt    = (int*)alloc((size_t)N * 4);
    int*   rowptr = (int*)alloc((size_t)(N + 1) * 4);
    int*   fillc  = (int*)alloc((size_t)N * 4);
    int*   bsum   = (int*)alloc(4096);
    int*   col    = (int*)alloc((size_t)E * 4);
    float* dinv   = (float*)alloc((size_t)N * 4);
    unsigned short* t0 = (unsigned short*)alloc(NF * 2);
    unsigned short* h  = (unsigned short*)alloc(NF * 2);
    unsigned short* z  = (unsigned short*)alloc(NF * 2);

    hipMemsetAsync(cnt, 0, (size_t)N * 4, stream);
    hipMemsetAsync(fillc, 0, (size_t)N * 4, stream);

    int eb = (E + 255) / 256;
    int NB = (N + 1023) / 1024;
    deg_kernel<<<eb, 256, 0, stream>>>(dstI, cnt, E);
    scan_partial<<<NB, 256, 0, stream>>>(cnt, bsum, N);
    scan_sums<<<1, 256, 0, stream>>>(bsum, NB);
    scan_final<<<NB, 256, 0, stream>>>(cnt, bsum, rowptr, N, E);
    deg_dinv<<<(N + 255) / 256, 256, 0, stream>>>(cnt, dinv, N);
    fill_kernel<<<eb, 256, 0, stream>>>(srcI, dstI, rowptr, fillc, col, E);

    int gb = (N + 63) / 64;
    int ab = (N + 15) / 16;

    // conv1: h = relu(agg(x @ W1))
    gemm_mfma<false><<<gb, 256, 0, stream>>>(x, W1, dinv, t0, N);
    agg_bf16<0><<<ab, 256, 0, stream>>>((const uint4*)t0, rowptr, col, dinv, b1, nullptr, h, nullptr, nullptr, N);
    // conv2: mu
    gemm_mfma<true><<<gb, 256, 0, stream>>>(h, Wmu, dinv, t0, N);
    agg_bf16<1><<<ab, 256, 0, stream>>>((const uint4*)t0, rowptr, col, dinv, bmu, muO, nullptr, nullptr, nullptr, N);
    // conv3: logvar + z
    gemm_mfma<true><<<gb, 256, 0, stream>>>(h, Wlv, dinv, t0, N);
    agg_bf16<2><<<ab, 256, 0, stream>>>((const uint4*)t0, rowptr, col, dinv, blv, lvO, z, eps, muO, N);
    // conv4: recon = sigmoid(agg(z @ W1))
    gemm_mfma<true><<<gb, 256, 0, stream>>>(z, W1, dinv, t0, N);
    agg_bf16<3><<<ab, 256, 0, stream>>>((const uint4*)t0, rowptr, col, dinv, b1, recon, nullptr, nullptr, nullptr, N);
}

// Round 3
// 425.144 us; speedup vs baseline: 1.5044x; 1.1007x over previous
//
#include <hip/hip_runtime.h>
#include <hip/hip_bf16.h>

#define FDIM 128

typedef __attribute__((ext_vector_type(8))) short short8;
typedef __attribute__((ext_vector_type(4))) float f32x4;

__device__ inline float bflo(unsigned u) { return __uint_as_float(u << 16); }
__device__ inline float bfhi(unsigned u) { return __uint_as_float(u & 0xffff0000u); }
__device__ inline unsigned short f2bf(float f) {
    unsigned u = __float_as_uint(f);
    u += 0x7fffu + ((u >> 16) & 1u);   // RNE
    return (unsigned short)(u >> 16);
}
__device__ inline unsigned pack2(float a, float b) {
    return (unsigned)f2bf(a) | ((unsigned)f2bf(b) << 16);
}

// ---------------- degree count ----------------
__global__ __launch_bounds__(256) void deg_kernel(const int* __restrict__ dst, int* __restrict__ cnt, int E) {
    int e = blockIdx.x * 256 + threadIdx.x;
    if (e < E) atomicAdd(&cnt[dst[e]], 1);
}

// ---------------- scan phase A ----------------
__global__ __launch_bounds__(256) void scan_partial(const int* __restrict__ cnt, int* __restrict__ bsum, int n) {
    __shared__ int sdata[256];
    int b = blockIdx.x, t = threadIdx.x;
    int base = b * 1024;
    int s = 0;
    for (int i = 0; i < 4; i++) {
        int idx = base + t * 4 + i;
        if (idx < n) s += cnt[idx];
    }
    sdata[t] = s;
    __syncthreads();
    for (int off = 128; off > 0; off >>= 1) {
        if (t < off) sdata[t] += sdata[t + off];
        __syncthreads();
    }
    if (t == 0) bsum[b] = sdata[0];
}

// ---------------- scan phase B: exclusive scan of block sums (nb <= 256) ----------------
__global__ __launch_bounds__(256) void scan_sums(int* __restrict__ bsum, int nb) {
    __shared__ int sdata[256];
    int t = threadIdx.x;
    int v = (t < nb) ? bsum[t] : 0;
    sdata[t] = v;
    __syncthreads();
    for (int off = 1; off < 256; off <<= 1) {
        int u = (t >= off) ? sdata[t - off] : 0;
        __syncthreads();
        sdata[t] += u;
        __syncthreads();
    }
    if (t < nb) bsum[t] = sdata[t] - v;
}

// ---------------- scan phase C ----------------
__global__ __launch_bounds__(256) void scan_final(const int* __restrict__ cnt, const int* __restrict__ bsum,
                                                  int* __restrict__ rowptr, int n, int E) {
    __shared__ int sdata[256];
    int b = blockIdx.x, t = threadIdx.x;
    int base = b * 1024;
    int loc[4];
    int s = 0;
    for (int i = 0; i < 4; i++) {
        int idx = base + t * 4 + i;
        int v = (idx < n) ? cnt[idx] : 0;
        loc[i] = s;
        s += v;
    }
    sdata[t] = s;
    __syncthreads();
    for (int off = 1; off < 256; off <<= 1) {
        int v = (t >= off) ? sdata[t - off] : 0;
        __syncthreads();
        sdata[t] += v;
        __syncthreads();
    }
    int texc = sdata[t] - s;
    int boff = bsum[b];
    for (int i = 0; i < 4; i++) {
        int idx = base + t * 4 + i;
        if (idx < n) rowptr[idx] = boff + texc + loc[i];
    }
    if (b == 0 && t == 0) rowptr[n] = E;
}

// ---------------- dinv ----------------
__global__ __launch_bounds__(256) void deg_dinv(const int* __restrict__ cnt, float* __restrict__ dinv, int n) {
    int i = blockIdx.x * 256 + threadIdx.x;
    if (i < n) dinv[i] = rsqrtf((float)(cnt[i] + 1));
}

// ---------------- CSR fill ----------------
__global__ __launch_bounds__(256) void fill_kernel(const int* __restrict__ srcI, const int* __restrict__ dstI,
                                                   const int* __restrict__ rowptr, int* __restrict__ fill,
                                                   int* __restrict__ col, int E) {
    int e = blockIdx.x * 256 + threadIdx.x;
    if (e < E) {
        int d = dstI[e];
        int pos = rowptr[d] + atomicAdd(&fill[d], 1);
        col[pos] = srcI[e];
    }
}

// ---------------- convert: x_tilde = bf16(x * dinv[row]), 8 elems/thread ----------------
__global__ __launch_bounds__(256) void conv_scale(const float* __restrict__ X, const float* __restrict__ dinv,
                                                  uint4* __restrict__ Y, int nf8) {
    int i = blockIdx.x * 256 + threadIdx.x;
    if (i >= nf8) return;
    int row = i >> 4;                 // 16 uint4-slots per 128-elem row
    float d = dinv[row];
    const float4* X4 = (const float4*)X;
    float4 f0 = X4[i * 2], f1 = X4[i * 2 + 1];
    uint4 o;
    o.x = pack2(f0.x * d, f0.y * d);
    o.y = pack2(f0.z * d, f0.w * d);
    o.z = pack2(f1.x * d, f1.y * d);
    o.w = pack2(f1.z * d, f1.w * d);
    Y[i] = o;
}

// ---------------- gather: G[j] = bf16( dinv[j] * (T[j] + sum_{s->j} T[s]) ) ----------------
// 16 nodes/block, 16 lanes/node, 8 bf16 feats (uint4) per lane. Inputs pre-scaled by dinv[src].
__global__ __launch_bounds__(256) void gather_agg(const uint4* __restrict__ T, const int* __restrict__ rowptr,
                                                  const int* __restrict__ col, const float* __restrict__ dinv,
                                                  uint4* __restrict__ G, int n) {
    int t = threadIdx.x;
    int lane16 = t & 15;
    int node = blockIdx.x * 16 + (t >> 4);
    if (node >= n) return;

    size_t ridx = (size_t)node * 16 + lane16;
    float acc[8];
    {
        uint4 v = T[ridx];  // self-loop
        acc[0] = bflo(v.x); acc[1] = bfhi(v.x); acc[2] = bflo(v.y); acc[3] = bfhi(v.y);
        acc[4] = bflo(v.z); acc[5] = bfhi(v.z); acc[6] = bflo(v.w); acc[7] = bfhi(v.w);
    }
    auto add8 = [&](uint4 v) {
        acc[0] += bflo(v.x); acc[1] += bfhi(v.x); acc[2] += bflo(v.y); acc[3] += bfhi(v.y);
        acc[4] += bflo(v.z); acc[5] += bfhi(v.z); acc[6] += bflo(v.w); acc[7] += bfhi(v.w);
    };

    int rp0 = rowptr[node], rp1 = rowptr[node + 1];
    for (int eb = rp0; eb < rp1; eb += 16) {
        int e = eb + lane16;
        int myc = (e < rp1) ? col[e] : 0;
        int m = rp1 - eb; if (m > 16) m = 16;
        int i = 0;
        for (; i + 4 <= m; i += 4) {
            int s0 = __shfl(myc, i, 16);
            int s1 = __shfl(myc, i + 1, 16);
            int s2 = __shfl(myc, i + 2, 16);
            int s3 = __shfl(myc, i + 3, 16);
            uint4 v0 = T[(size_t)s0 * 16 + lane16];
            uint4 v1 = T[(size_t)s1 * 16 + lane16];
            uint4 v2 = T[(size_t)s2 * 16 + lane16];
            uint4 v3 = T[(size_t)s3 * 16 + lane16];
            add8(v0); add8(v1); add8(v2); add8(v3);
        }
        for (; i < m; i++) {
            int s = __shfl(myc, i, 16);
            add8(T[(size_t)s * 16 + lane16]);
        }
    }

    float dj = dinv[node];
    uint4 o;
    o.x = pack2(acc[0] * dj, acc[1] * dj);
    o.y = pack2(acc[2] * dj, acc[3] * dj);
    o.z = pack2(acc[4] * dj, acc[5] * dj);
    o.w = pack2(acc[6] * dj, acc[7] * dj);
    G[ridx] = o;
}

// ---------------- MFMA GEMM single-W with epilogue ----------------
// G: n x 128 bf16 (aggregated). out = epi(G @ W + bias).
// MODE 0: h_tilde = relu(v) * dinv[row] -> bf16.   MODE 1: recon = sigmoid(v) -> fp32.
template<int MODE>
__global__ __launch_bounds__(256) void gemm_epi(const unsigned short* __restrict__ Gm, const float* __restrict__ W,
                                                const float* __restrict__ bias, const float* __restrict__ dinv,
                                                void* __restrict__ out, int n) {
    __shared__ unsigned short Wt[128][136];
    int t = threadIdx.x;
    #pragma unroll 4
    for (int i = 0; i < 64; i++) {
        int idx = i * 256 + t;
        Wt[idx & 127][idx >> 7] = f2bf(W[idx]);
    }
    __syncthreads();

    int wave = t >> 6, lane = t & 63;
    int quad = lane >> 4, mrow = lane & 15;
    int row0 = blockIdx.x * 64 + wave * 16;
    int gr = row0 + mrow; if (gr >= n) gr = n - 1;

    f32x4 acc[8];
    #pragma unroll
    for (int i = 0; i < 8; i++) acc[i] = (f32x4){0.f, 0.f, 0.f, 0.f};

    #pragma unroll
    for (int kb = 0; kb < 4; kb++) {
        int k0 = kb * 32 + quad * 8;
        union { uint4 u4; short8 s8; } cv;
        cv.u4 = *(const uint4*)(Gm + (size_t)gr * FDIM + k0);
        short8 a = cv.s8;
        #pragma unroll
        for (int tile = 0; tile < 8; tile++) {
            short8 b = *(const short8*)&Wt[tile * 16 + mrow][k0];
            acc[tile] = __builtin_amdgcn_mfma_f32_16x16x32_bf16(a, b, acc[tile], 0, 0, 0);
        }
    }

    #pragma unroll
    for (int r = 0; r < 4; r++) {
        int rowg = row0 + quad * 4 + r;
        if (rowg >= n) continue;
        if (MODE == 0) {
            float dj = dinv[rowg];
            unsigned short* Y = (unsigned short*)out;
            #pragma unroll
            for (int tile = 0; tile < 8; tile++) {
                int c = tile * 16 + mrow;
                float v = fmaxf(acc[tile][r] + bias[c], 0.f) * dj;
                Y[(size_t)rowg * FDIM + c] = f2bf(v);
            }
        } else {
            float* Y = (float*)out;
            #pragma unroll
            for (int tile = 0; tile < 8; tile++) {
                int c = tile * 16 + mrow;
                float v = acc[tile][r] + bias[c];
                Y[(size_t)rowg * FDIM + c] = 1.f / (1.f + expf(-v));
            }
        }
    }
}

// ---------------- MFMA GEMM dual-W: mu, logvar, z_tilde ----------------
// mu = G@Wmu + bmu (fp32 out); lv = G@Wlv + blv (fp32 out);
// z_tilde = (eps*exp(0.5*lv) + mu) * dinv[row] (bf16 out).
__global__ __launch_bounds__(256) void gemm_dual(const unsigned short* __restrict__ Gm,
                                                 const float* __restrict__ Wmu, const float* __restrict__ Wlv,
                                                 const float* __restrict__ bmu, const float* __restrict__ blv,
                                                 const float* __restrict__ eps, const float* __restrict__ dinv,
                                                 float* __restrict__ muO, float* __restrict__ lvO,
                                                 unsigned short* __restrict__ zt, int n) {
    __shared__ unsigned short Wa[128][136];
    __shared__ unsigned short Wb[128][136];
    int t = threadIdx.x;
    #pragma unroll 4
    for (int i = 0; i < 64; i++) {
        int idx = i * 256 + t;
        Wa[idx & 127][idx >> 7] = f2bf(Wmu[idx]);
        Wb[idx & 127][idx >> 7] = f2bf(Wlv[idx]);
    }
    __syncthreads();

    int wave = t >> 6, lane = t & 63;
    int quad = lane >> 4, mrow = lane & 15;
    int row0 = blockIdx.x * 64 + wave * 16;
    int gr = row0 + mrow; if (gr >= n) gr = n - 1;

    f32x4 am[8], al[8];
    #pragma unroll
    for (int i = 0; i < 8; i++) { am[i] = (f32x4){0.f,0.f,0.f,0.f}; al[i] = (f32x4){0.f,0.f,0.f,0.f}; }

    #pragma unroll
    for (int kb = 0; kb < 4; kb++) {
        int k0 = kb * 32 + quad * 8;
        union { uint4 u4; short8 s8; } cv;
        cv.u4 = *(const uint4*)(Gm + (size_t)gr * FDIM + k0);
        short8 a = cv.s8;
        #pragma unroll
        for (int tile = 0; tile < 8; tile++) {
            short8 b0 = *(const short8*)&Wa[tile * 16 + mrow][k0];
            am[tile] = __builtin_amdgcn_mfma_f32_16x16x32_bf16(a, b0, am[tile], 0, 0, 0);
            short8 b1 = *(const short8*)&Wb[tile * 16 + mrow][k0];
            al[tile] = __builtin_amdgcn_mfma_f32_16x16x32_bf16(a, b1, al[tile], 0, 0, 0);
        }
    }

    #pragma unroll
    for (int r = 0; r < 4; r++) {
        int rowg = row0 + quad * 4 + r;
        if (rowg >= n) continue;
        float dj = dinv[rowg];
        #pragma unroll
        for (int tile = 0; tile < 8; tile++) {
            int c = tile * 16 + mrow;
            size_t o = (size_t)rowg * FDIM + c;
            float m = am[tile][r] + bmu[c];
            float l = al[tile][r] + blv[c];
            muO[o] = m;
            lvO[o] = l;
            float z = eps[o] * expf(0.5f * l) + m;
            zt[o] = f2bf(z * dj);
        }
    }
}

extern "C" void kernel_launch(void* const* d_in, const int* in_sizes, int n_in,
                              void* d_out, int out_size, void* d_ws, size_t ws_size,
                              hipStream_t stream) {
    const int F = FDIM;
    const int N = in_sizes[0] / F;
    const int E = in_sizes[1] / 2;

    const float* x   = (const float*)d_in[0];
    const int*   ei  = (const int*)d_in[1];
    const int*   srcI = ei;
    const int*   dstI = ei + E;
    const float* eps = (const float*)d_in[2];
    const float* W1  = (const float*)d_in[3];
    const float* b1  = (const float*)d_in[4];
    const float* Wmu = (const float*)d_in[5];
    const float* bmu = (const float*)d_in[6];
    const float* Wlv = (const float*)d_in[7];
    const float* blv = (const float*)d_in[8];

    float* recon = (float*)d_out;
    size_t NF = (size_t)N * F;
    float* muO = recon + NF;
    float* lvO = recon + 2 * NF;

    size_t off = 0;
    auto alloc = [&](size_t bytes) -> void* {
        void* p = (char*)d_ws + off;
        off += (bytes + 255) & ~(size_t)255;
        return p;
    };
    int*   cnt    = (int*)alloc((size_t)N * 4);
    int*   rowptr = (int*)alloc((size_t)(N + 1) * 4);
    int*   fillc  = (int*)alloc((size_t)N * 4);
    int*   bsum   = (int*)alloc(4096);
    int*   col    = (int*)alloc((size_t)E * 4);
    float* dinv   = (float*)alloc((size_t)N * 4);
    unsigned short* bufA = (unsigned short*)alloc(NF * 2);  // scaled features (x~, h~, z~)
    unsigned short* bufB = (unsigned short*)alloc(NF * 2);  // aggregated (g1, g2, g3)

    hipMemsetAsync(cnt, 0, (size_t)N * 4, stream);
    hipMemsetAsync(fillc, 0, (size_t)N * 4, stream);

    int eb = (E + 255) / 256;
    int NB = (N + 1023) / 1024;
    deg_kernel<<<eb, 256, 0, stream>>>(dstI, cnt, E);
    scan_partial<<<NB, 256, 0, stream>>>(cnt, bsum, N);
    scan_sums<<<1, 256, 0, stream>>>(bsum, NB);
    scan_final<<<NB, 256, 0, stream>>>(cnt, bsum, rowptr, N, E);
    deg_dinv<<<(N + 255) / 256, 256, 0, stream>>>(cnt, dinv, N);
    fill_kernel<<<eb, 256, 0, stream>>>(srcI, dstI, rowptr, fillc, col, E);

    int nf8 = (int)(NF / 8);
    int cb = (nf8 + 255) / 256;
    int ab = (N + 15) / 16;
    int gb = (N + 63) / 64;

    // x~ = bf16(x * dinv)
    conv_scale<<<cb, 256, 0, stream>>>(x, dinv, (uint4*)bufA, nf8);
    // g1 = Agg(x~)
    gather_agg<<<ab, 256, 0, stream>>>((const uint4*)bufA, rowptr, col, dinv, (uint4*)bufB, N);
    // h~ = relu(g1 @ W1 + b1) * dinv
    gemm_epi<0><<<gb, 256, 0, stream>>>(bufB, W1, b1, dinv, bufA, N);
    // g2 = Agg(h~)
    gather_agg<<<ab, 256, 0, stream>>>((const uint4*)bufA, rowptr, col, dinv, (uint4*)bufB, N);
    // mu, logvar, z~
    gemm_dual<<<gb, 256, 0, stream>>>(bufB, Wmu, Wlv, bmu, blv, eps, dinv, muO, lvO, bufA, N);
    // g3 = Agg(z~)
    gather_agg<<<ab, 256, 0, stream>>>((const uint4*)bufA, rowptr, col, dinv, (uint4*)bufB, N);
    // recon = sigmoid(g3 @ W1 + b1)
    gemm_epi<1><<<gb, 256, 0, stream>>>(bufB, W1, b1, nullptr, recon, N);
}